// Round 1
// baseline (887.736 us; speedup 1.0000x reference)
//
#include <hip/hip_runtime.h>
#include <hip/hip_bf16.h>

// Edge-MLP: out = relu(cat(v_i,v_j,e_ij) @ W1 + b1) @ W2 + b2
// E=1e6, d_in=160, HID=64, OUT=64. fp32 in/out, bf16 MFMA compute.
//
// Memory-bound problem: 896 MB min traffic -> ~142us floor @6.3TB/s.
// This version removes the H LDS round-trip via a hidden-dim permutation:
//   GEMM1 computed operand-swapped:  H^T = W1phys^T @ X^T   (mfma(w1,af))
//   with W1phys[:,p] = W1[:,pi(p)], pi(p) = ((p>>2)&3)*8 + ((p>>4)&1)*4
//                                         + (p&3) + (p>>5)*32.
//   Then lane (q,r)'s GEMM1 C/D regs acc[mt][g] hold exactly
//   Hlog[e0+r][s*32+q*8+j] with s=mt>>1, j=(mt&1)*4+g  — i.e. the GEMM2
//   B-fragment, with ZERO data movement (no LDS, no shuffles).
//   GEMM2 operand-swapped too: out^T = W2^T @ H^T, so C/D gives each lane
//   4 consecutive out-channels -> 4x dwordx4 stores (was 16 scalar).
// Input loads for tile t+stride are issued right after tile t's cvt,
// so ~10KB/wave stays in flight under the whole MFMA+store phase.

typedef __bf16 bf16x8 __attribute__((ext_vector_type(8)));
typedef float  f32x4  __attribute__((ext_vector_type(4)));

__device__ inline bf16x8 cvt8(float4 a, float4 b) {
    bf16x8 o;
    o[0] = (__bf16)a.x; o[1] = (__bf16)a.y; o[2] = (__bf16)a.z; o[3] = (__bf16)a.w;
    o[4] = (__bf16)b.x; o[5] = (__bf16)b.y; o[6] = (__bf16)b.z; o[7] = (__bf16)b.w;
    return o;
}

__global__ __launch_bounds__(256, 4)
void edge_mlp_kernel(const float* __restrict__ v_i,
                     const float* __restrict__ v_j,
                     const float* __restrict__ e_ij,
                     const float* __restrict__ W1,
                     const float* __restrict__ b1,
                     const float* __restrict__ W2,
                     const float* __restrict__ b2,
                     float* __restrict__ out,
                     int E)
{
    // A-fragment packing (operand-swapped GEMMs):
    // frag (ks,mt): lane l holds W[ks*32 + (l>>4)*8 + j][col], j=0..7
    __shared__ __align__(16) __bf16 w1f[20 * 64 * 8];   // 20 KB: 5 k-steps x 4 m-tiles
    __shared__ __align__(16) __bf16 w2f[8 * 64 * 8];    //  8 KB: 2 k-steps x 4 m-tiles

    const int tid = threadIdx.x;

    // ---- pack W1 into A-fragment order with hidden-permutation pi ----
    // col_phys p = mt*16 + r_  ->  col_logical pi(p)
    for (int idx = tid; idx < 20 * 64; idx += 256) {
        int f = idx >> 6, l = idx & 63;
        int ks = f >> 2, mt = f & 3;
        int kb = ks * 32 + ((l >> 4) << 3);
        int r_ = l & 15;
        int c  = ((mt >> 1) << 5) + ((r_ >> 2) << 3) + ((mt & 1) << 2) + (r_ & 3);
        #pragma unroll
        for (int j = 0; j < 8; ++j)
            w1f[idx * 8 + j] = (__bf16)W1[(kb + j) * 64 + c];
    }
    // ---- pack W2 (k axis = logical hidden; no permutation needed) ----
    for (int idx = tid; idx < 8 * 64; idx += 256) {
        int f = idx >> 6, l = idx & 63;
        int s = f >> 2, n = f & 3;
        int kb = s * 32 + ((l >> 4) << 3);
        int c  = n * 16 + (l & 15);
        #pragma unroll
        for (int j = 0; j < 8; ++j)
            w2f[idx * 8 + j] = (__bf16)W2[(kb + j) * 64 + c];
    }
    __syncthreads();

    const int wave = tid >> 6;
    const int lane = tid & 63;
    const int q = lane >> 4;   // quad id (0..3)
    const int r = lane & 15;   // intra-quad lane (0..15)

    // b1 in logical order at pi-mapped slots: b1v[mt][g] = b1[(mt>>1)*32 + q*8 + (mt&1)*4 + g]
    float4 b1v[4];
    b1v[0] = *(const float4*)(b1 + q * 8);
    b1v[1] = *(const float4*)(b1 + q * 8 + 4);
    b1v[2] = *(const float4*)(b1 + 32 + q * 8);
    b1v[3] = *(const float4*)(b1 + 32 + q * 8 + 4);
    // b2v[mo][g] = b2[mo*16 + q*4 + g]
    float4 b2v[4];
    #pragma unroll
    for (int mo = 0; mo < 4; ++mo)
        b2v[mo] = *(const float4*)(b2 + mo * 16 + q * 4);

    const long long ntiles = ((long long)E + 15) >> 4;
    const long long stride = (long long)gridDim.x * 4;
    long long t = (long long)blockIdx.x * 4 + wave;

    if (t >= ntiles) return;

    float4 x[10];

    // ---- prologue: load first tile ----
    {
        long long row = (t << 4) + r;
        if (row > (long long)E - 1) row = (long long)E - 1;
        const float* pvi = v_i + row * 64 + q * 8;
        const float* pvj = v_j + row * 64 + q * 8;
        const float* pe  = e_ij + row * 32 + q * 8;
        x[0] = *(const float4*)(pvi);
        x[1] = *(const float4*)(pvi + 4);
        x[2] = *(const float4*)(pvi + 32);
        x[3] = *(const float4*)(pvi + 36);
        x[4] = *(const float4*)(pvj);
        x[5] = *(const float4*)(pvj + 4);
        x[6] = *(const float4*)(pvj + 32);
        x[7] = *(const float4*)(pvj + 36);
        x[8] = *(const float4*)(pe);
        x[9] = *(const float4*)(pe + 4);
    }

    while (t < ntiles) {
        const long long e0 = t << 4;

        // consume staged loads -> bf16 A... (X^T B-fragments)
        bf16x8 af[5];
        af[0] = cvt8(x[0], x[1]);
        af[1] = cvt8(x[2], x[3]);
        af[2] = cvt8(x[4], x[5]);
        af[3] = cvt8(x[6], x[7]);
        af[4] = cvt8(x[8], x[9]);

        // ---- issue next tile's loads; stay in flight under all compute ----
        const long long tn = t + stride;
        if (tn < ntiles) {
            long long row = (tn << 4) + r;
            if (row > (long long)E - 1) row = (long long)E - 1;
            const float* pvi = v_i + row * 64 + q * 8;
            const float* pvj = v_j + row * 64 + q * 8;
            const float* pe  = e_ij + row * 32 + q * 8;
            x[0] = *(const float4*)(pvi);
            x[1] = *(const float4*)(pvi + 4);
            x[2] = *(const float4*)(pvi + 32);
            x[3] = *(const float4*)(pvi + 36);
            x[4] = *(const float4*)(pvj);
            x[5] = *(const float4*)(pvj + 4);
            x[6] = *(const float4*)(pvj + 32);
            x[7] = *(const float4*)(pvj + 36);
            x[8] = *(const float4*)(pe);
            x[9] = *(const float4*)(pe + 4);
        }

        // ---- GEMM1 (swapped): Hphys^T[64x16] = W1phys^T[64x160] @ X^T[160x16] ----
        f32x4 acc[4] = {{0.f,0.f,0.f,0.f},{0.f,0.f,0.f,0.f},
                        {0.f,0.f,0.f,0.f},{0.f,0.f,0.f,0.f}};
        #pragma unroll
        for (int ks = 0; ks < 5; ++ks) {
            #pragma unroll
            for (int mt = 0; mt < 4; ++mt) {
                bf16x8 aw = *(const bf16x8*)&w1f[((ks * 4 + mt) * 64 + lane) * 8];
                acc[mt] = __builtin_amdgcn_mfma_f32_16x16x32_bf16(aw, af[ks], acc[mt], 0, 0, 0);
            }
        }

        // ---- bias + ReLU + pack: acc[2s..2s+1] IS GEMM2's B-fragment (pi trick) ----
        bf16x8 hf[2];
        #pragma unroll
        for (int s = 0; s < 2; ++s) {
            #pragma unroll
            for (int g = 0; g < 4; ++g) {
                float h0 = acc[2 * s][g]     + b1v[2 * s][g];
                float h1 = acc[2 * s + 1][g] + b1v[2 * s + 1][g];
                hf[s][g]     = (__bf16)(h0 > 0.f ? h0 : 0.f);
                hf[s][4 + g] = (__bf16)(h1 > 0.f ? h1 : 0.f);
            }
        }

        // ---- GEMM2 (swapped): out^T[64x16] = W2^T[64x64] @ H^T[64x16] ----
        f32x4 accO[4] = {{0.f,0.f,0.f,0.f},{0.f,0.f,0.f,0.f},
                         {0.f,0.f,0.f,0.f},{0.f,0.f,0.f,0.f}};
        #pragma unroll
        for (int s = 0; s < 2; ++s) {
            #pragma unroll
            for (int mo = 0; mo < 4; ++mo) {
                bf16x8 aw = *(const bf16x8*)&w2f[((s * 4 + mo) * 64 + lane) * 8];
                accO[mo] = __builtin_amdgcn_mfma_f32_16x16x32_bf16(aw, hf[s], accO[mo], 0, 0, 0);
            }
        }

        // ---- epilogue: lane (q,r) owns out[e0+r][mo*16+q*4 .. +3] -> dwordx4 ----
        const long long rowo = e0 + r;
        if (e0 + 16 <= (long long)E) {
            float* po = out + rowo * 64 + q * 4;
            #pragma unroll
            for (int mo = 0; mo < 4; ++mo) {
                float4 v;
                v.x = accO[mo][0] + b2v[mo].x;
                v.y = accO[mo][1] + b2v[mo].y;
                v.z = accO[mo][2] + b2v[mo].z;
                v.w = accO[mo][3] + b2v[mo].w;
                *(float4*)(po + mo * 16) = v;
            }
        } else if (rowo < (long long)E) {
            float* po = out + rowo * 64 + q * 4;
            #pragma unroll
            for (int mo = 0; mo < 4; ++mo) {
                float4 v;
                v.x = accO[mo][0] + b2v[mo].x;
                v.y = accO[mo][1] + b2v[mo].y;
                v.z = accO[mo][2] + b2v[mo].z;
                v.w = accO[mo][3] + b2v[mo].w;
                *(float4*)(po + mo * 16) = v;
            }
        }

        t = tn;
    }
}

extern "C" void kernel_launch(void* const* d_in, const int* in_sizes, int n_in,
                              void* d_out, int out_size, void* d_ws, size_t ws_size,
                              hipStream_t stream) {
    const float* v_i  = (const float*)d_in[0];
    const float* v_j  = (const float*)d_in[1];
    const float* e_ij = (const float*)d_in[2];
    const float* W1   = (const float*)d_in[3];
    const float* b1   = (const float*)d_in[4];
    const float* W2   = (const float*)d_in[5];
    const float* b2   = (const float*)d_in[6];
    float* out = (float*)d_out;

    const int E = in_sizes[0] / 64;

    // 1024 blocks x 4 waves: 4 blocks/CU resident (LDS 28KB, VGPR<=128),
    // grid-stride over 62500 16-edge tiles.
    edge_mlp_kernel<<<dim3(1024), dim3(256), 0, stream>>>(
        v_i, v_j, e_ij, W1, b1, W2, b2, out, E);
}